// Round 3
// baseline (472.456 us; speedup 1.0000x reference)
//
#include <hip/hip_runtime.h>
#include <hip/hip_bf16.h>
#include <stdint.h>

#define D 1024
#define TEMP_INV (1.0f / 0.92f)
#define LOG2E 1.44269504f
#define EPS 1e-6f

typedef float f32x4_t __attribute__((ext_vector_type(4)));
typedef int   i32x4_t __attribute__((ext_vector_type(4)));
typedef int   i32x8_t __attribute__((ext_vector_type(8)));

typedef __attribute__((address_space(3))) void as3_void;
typedef const __attribute__((address_space(1))) void as1_void_c;

__device__ __forceinline__ void async_copy16(const uint8_t* g, uint8_t* l) {
    __builtin_amdgcn_global_load_lds((as1_void_c*)g, (as3_void*)l, 16, 0, 0);
}

// compiler memory fence + raw workgroup barrier (NO implicit vmcnt drain)
#define MEMFENCE() asm volatile("" ::: "memory")
#define BARRIER()  do { MEMFENCE(); __builtin_amdgcn_s_barrier(); MEMFENCE(); } while (0)

// ---------------------------------------------------------------------------
// Kernel 1: unchanged (verified). fp8 convert + norms + s1 + rowsum zero.
// ---------------------------------------------------------------------------
__global__ __launch_bounds__(256) void prep_kernel(
    const float* __restrict__ q, const float* __restrict__ p,
    const float* __restrict__ neg,
    uint8_t* __restrict__ Qb, uint8_t* __restrict__ Nb,
    float* __restrict__ iq, float* __restrict__ inx,
    float* __restrict__ s1, float* __restrict__ rowsum, int B)
{
    const int lane = threadIdx.x & 63;
    const int wid  = threadIdx.x >> 6;
    const int row  = blockIdx.x * 4 + wid;

    if (row < B) {
        const float4* qr = (const float4*)(q + (size_t)row * D);
        const float4* pr = (const float4*)(p + (size_t)row * D);
        int* qo = (int*)(Qb + (size_t)row * D);
        float qq = 0.f, pp = 0.f, qp = 0.f;
        #pragma unroll
        for (int i = 0; i < 4; ++i) {
            const int idx = i * 64 + lane;
            const float4 qv = qr[idx];
            const float4 pv = pr[idx];
            int pk = __builtin_amdgcn_cvt_pk_fp8_f32(qv.x, qv.y, 0, false);
            pk     = __builtin_amdgcn_cvt_pk_fp8_f32(qv.z, qv.w, pk, true);
            qo[idx] = pk;
            qq += qv.x*qv.x + qv.y*qv.y + qv.z*qv.z + qv.w*qv.w;
            pp += pv.x*pv.x + pv.y*pv.y + pv.z*pv.z + pv.w*pv.w;
            qp += qv.x*pv.x + qv.y*pv.y + qv.z*pv.z + qv.w*pv.w;
        }
        #pragma unroll
        for (int off = 32; off > 0; off >>= 1) {
            qq += __shfl_down(qq, off, 64);
            pp += __shfl_down(pp, off, 64);
            qp += __shfl_down(qp, off, 64);
        }
        if (lane == 0) {
            float qnv = sqrtf(qq);
            iq[row] = (TEMP_INV * LOG2E) / fmaxf(qnv, 1e-20f);
            float den = fmaxf(qnv * sqrtf(pp), EPS);
            s1[row] = expf((qp / den) * TEMP_INV);   // exact reference path
            rowsum[row] = 0.0f;
        }
    } else {
        const int r2 = row - B;
        const float4* nr = (const float4*)(neg + (size_t)r2 * D);
        int* no = (int*)(Nb + (size_t)r2 * D);
        float ss = 0.f;
        #pragma unroll
        for (int i = 0; i < 4; ++i) {
            const int idx = i * 64 + lane;
            const float4 nv = nr[idx];
            int pk = __builtin_amdgcn_cvt_pk_fp8_f32(nv.x, nv.y, 0, false);
            pk     = __builtin_amdgcn_cvt_pk_fp8_f32(nv.z, nv.w, pk, true);
            no[idx] = pk;
            ss += nv.x*nv.x + nv.y*nv.y + nv.z*nv.z + nv.w*nv.w;
        }
        #pragma unroll
        for (int off = 32; off > 0; off >>= 1) ss += __shfl_down(ss, off, 64);
        if (lane == 0) inx[r2] = 1.0f / fmaxf(sqrtf(ss), 1e-20f);
    }
}

// ---------------------------------------------------------------------------
// Kernel 2: 256x256 tile, 8 waves (2M x 4N), BK=128 fp8, double-buffered
// 128 KiB LDS, 4-phase K-iter with counted vmcnt + setprio.
//
// Register budget fix (round 3): rocprof showed VGPR_Count=128 (unified
// VGPR+AGPR total) in both prior rounds -> backend targeted 4 waves/SIMD,
// but acc[8][4] alone is 128 f32 -> 1.3 KB/thread scratch spill (675 MB
// HBM writes/dispatch). LDS (128 KiB) already limits the CU to ONE 8-wave
// block = 2 waves/SIMD, so explicitly pin amdgpu_waves_per_eu(2,2) ->
// 512-reg file / 2 = 256 unified regs/wave. Live set ~220 fits; spill -> 0.
// ---------------------------------------------------------------------------
__global__ __launch_bounds__(512)
__attribute__((amdgpu_waves_per_eu(2, 2)))
void gemm_exp_rowsum(
    const uint8_t* __restrict__ Qb, const uint8_t* __restrict__ Nb,
    const float* __restrict__ iq, const float* __restrict__ inx,
    float* __restrict__ rowsum)
{
    __shared__ __align__(16) uint8_t As[2][256 * 128];   // 2 x 32 KB
    __shared__ __align__(16) uint8_t Bs[2][256 * 128];   // 2 x 32 KB

    const int tid = threadIdx.x;          // 0..511
    const int i0 = blockIdx.y * 256;      // Q rows
    const int j0 = blockIdx.x * 256;      // Neg rows

    const int lane = tid & 63;
    const int wid  = tid >> 6;            // 0..7
    const int wm   = wid & 1;             // wave row (2x4 wave grid)
    const int wn   = wid >> 1;            // wave col 0..3
    const int quad = lane >> 4;
    const int lc   = lane & 15;

    // --- staging thread map: 512 thr x 16B = one 64-row round; 4 rounds/tile
    const int r_in = tid >> 3;            // 0..63
    const int slot = tid & 7;
    const int v    = slot ^ (r_in & 7);
    const int csw  = ((v & 3) << 1) | (v >> 2);    // pi^-1(v)
    const uint8_t* gA0 = Qb + (size_t)(i0 + r_in) * D + csw * 16;
    const uint8_t* gB0 = Nb + (size_t)(j0 + r_in) * D + csw * 16;

    auto stage = [&](int buf, int ktarg) {     // 8 global_load_lds / thread
        const uint8_t* ga = gA0 + ktarg * 128;
        const uint8_t* gb = gB0 + ktarg * 128;
        #pragma unroll
        for (int c = 0; c < 4; ++c) {
            async_copy16(ga + (size_t)c * (64 * D), &As[buf][tid * 16 + c * 8192]);
            async_copy16(gb + (size_t)c * (64 * D), &Bs[buf][tid * 16 + c * 8192]);
        }
    };

    // --- LDS read-side swizzle (verified): slot of chunk 2q / 2q+1
    const int slo = (quad ^ (lc & 7)) * 16;
    const int shi = slo ^ 64;

    f32x4_t acc[8][4];
    #pragma unroll
    for (int mi = 0; mi < 8; ++mi)
        #pragma unroll
        for (int ni = 0; ni < 4; ++ni)
            acc[mi][ni] = (f32x4_t){0.f, 0.f, 0.f, 0.f};

    union Frag { i32x8_t v8; i32x4_t v4[2]; };

    // --- prologue: 2 tiles in flight, wait only for the first
    stage(0, 0);
    stage(1, 1);
    asm volatile("s_waitcnt vmcnt(8)" ::: "memory");   // tile 0 landed
    BARRIER();

    #pragma unroll
    for (int kt = 0; kt < 8; ++kt) {
        const int cb = kt & 1;
        const uint8_t* Ab = &As[cb][(wm * 128 + lc) * 128];
        const uint8_t* Bb = &Bs[cb][(wn * 64  + lc) * 128];

        // B fragments for the whole iter (held in regs across phases)
        Frag bfr[4];
        #pragma unroll
        for (int ni = 0; ni < 4; ++ni) {
            bfr[ni].v4[0] = *(const i32x4_t*)(Bb + ni * 2048 + slo);
            bfr[ni].v4[1] = *(const i32x4_t*)(Bb + ni * 2048 + shi);
        }

        // 4 phases x {read A-pair; barrier; lgkm(0); prio1; 8 MFMA; prio0; barrier}
        #pragma unroll
        for (int ph = 0; ph < 4; ++ph) {
            Frag a0, a1;
            a0.v4[0] = *(const i32x4_t*)(Ab + (2 * ph + 0) * 2048 + slo);
            a0.v4[1] = *(const i32x4_t*)(Ab + (2 * ph + 0) * 2048 + shi);
            a1.v4[0] = *(const i32x4_t*)(Ab + (2 * ph + 1) * 2048 + slo);
            a1.v4[1] = *(const i32x4_t*)(Ab + (2 * ph + 1) * 2048 + shi);
            BARRIER();
            asm volatile("s_waitcnt lgkmcnt(0)" ::: "memory");
            __builtin_amdgcn_sched_barrier(0);
            __builtin_amdgcn_s_setprio(1);
            #pragma unroll
            for (int ni = 0; ni < 4; ++ni) {
                acc[2 * ph + 0][ni] = __builtin_amdgcn_mfma_scale_f32_16x16x128_f8f6f4(
                    a0.v8, bfr[ni].v8, acc[2 * ph + 0][ni],
                    0 /*A=fp8*/, 0 /*B=fp8*/, 0, 127, 0, 127);
                acc[2 * ph + 1][ni] = __builtin_amdgcn_mfma_scale_f32_16x16x128_f8f6f4(
                    a1.v8, bfr[ni].v8, acc[2 * ph + 1][ni],
                    0, 0, 0, 127, 0, 127);
            }
            __builtin_amdgcn_s_setprio(0);
            BARRIER();
        }

        // end of iter: all waves are past their LDS reads of buf[cb] -> restage.
        if (kt < 6) {
            stage(cb, kt + 2);                              // 8 new loads
            asm volatile("s_waitcnt vmcnt(8)" ::: "memory"); // wait tile kt+1 only
        } else {
            asm volatile("s_waitcnt vmcnt(0)" ::: "memory"); // drain for last tile
        }
        BARRIER();
    }

    // --- epilogue: e = exp2(dot * iq_i * in_j); 16-lane row-reduce; atomic.
    // C/D layout (16x16): col = lane&15, row = quad*4 + reg (verified).
    float inl[4];
    #pragma unroll
    for (int ni = 0; ni < 4; ++ni)
        inl[ni] = inx[j0 + wn * 64 + ni * 16 + lc];

    #pragma unroll
    for (int mi = 0; mi < 8; ++mi) {
        const int rbase = i0 + wm * 128 + mi * 16 + quad * 4;
        const float4 qv = *(const float4*)&iq[rbase];   // iq includes T^-1*log2e
        float qa[4] = {qv.x, qv.y, qv.z, qv.w};
        float rs[4] = {0.f, 0.f, 0.f, 0.f};
        #pragma unroll
        for (int ni = 0; ni < 4; ++ni) {
            #pragma unroll
            for (int r = 0; r < 4; ++r)
                rs[r] += __builtin_amdgcn_exp2f(acc[mi][ni][r] * qa[r] * inl[ni]);
        }
        #pragma unroll
        for (int m = 1; m < 16; m <<= 1) {
            #pragma unroll
            for (int r = 0; r < 4; ++r) rs[r] += __shfl_xor(rs[r], m, 64);
        }
        if (lc == 0) {
            #pragma unroll
            for (int r = 0; r < 4; ++r) atomicAdd(&rowsum[rbase + r], rs[r]);
        }
    }
}

// ---------------------------------------------------------------------------
// Kernel 3: unchanged (verified). loss = mean_b( log(s1+s2) - log(s1) ).
// ---------------------------------------------------------------------------
__global__ __launch_bounds__(256) void finalize_kernel(
    const float* __restrict__ s1, const float* __restrict__ rowsum,
    float* __restrict__ out, int B, float invN)
{
    __shared__ float red[4];
    const float4* s4 = (const float4*)s1;
    const float4* r4 = (const float4*)rowsum;
    float acc = 0.f;
    for (int i = threadIdx.x; i < B / 4; i += 256) {
        float4 a = s4[i];
        float4 s = r4[i];
        acc += __logf(a.x + s.x * invN) - __logf(a.x);
        acc += __logf(a.y + s.y * invN) - __logf(a.y);
        acc += __logf(a.z + s.z * invN) - __logf(a.z);
        acc += __logf(a.w + s.w * invN) - __logf(a.w);
    }
    #pragma unroll
    for (int off = 32; off > 0; off >>= 1) acc += __shfl_down(acc, off, 64);
    if ((threadIdx.x & 63) == 0) red[threadIdx.x >> 6] = acc;
    __syncthreads();
    if (threadIdx.x == 0)
        out[0] = (red[0] + red[1] + red[2] + red[3]) / (float)B;
}

extern "C" void kernel_launch(void* const* d_in, const int* in_sizes, int n_in,
                              void* d_out, int out_size, void* d_ws, size_t ws_size,
                              hipStream_t stream) {
    const float* q   = (const float*)d_in[0];
    const float* p   = (const float*)d_in[1];
    const float* neg = (const float*)d_in[2];
    const int B = in_sizes[0] / D;
    const int N = in_sizes[2] / D;

    char* ws = (char*)d_ws;
    uint8_t* Qb     = (uint8_t*)ws;
    uint8_t* Nb     = (uint8_t*)(ws + (size_t)B * D);
    float*   iq     = (float*)(ws + (size_t)(B + N) * D);
    float*   inx    = iq + B;
    float*   s1     = inx + N;
    float*   rowsum = s1 + B;

    prep_kernel<<<(B + N) / 4, 256, 0, stream>>>(q, p, neg, Qb, Nb, iq, inx, s1, rowsum, B);
    gemm_exp_rowsum<<<dim3(N / 256, B / 256), 512, 0, stream>>>(Qb, Nb, iq, inx, rowsum);
    finalize_kernel<<<1, 256, 0, stream>>>(s1, rowsum, (float*)d_out, B, 1.0f / (float)N);
}

// Round 4
// 254.488 us; speedup vs baseline: 1.8565x; 1.8565x over previous
//
#include <hip/hip_runtime.h>
#include <hip/hip_bf16.h>
#include <stdint.h>

#define D 1024
#define TEMP_INV (1.0f / 0.92f)
#define LOG2E 1.44269504f
#define EPS 1e-6f

typedef float f32x4_t __attribute__((ext_vector_type(4)));
typedef int   i32x4_t __attribute__((ext_vector_type(4)));
typedef int   i32x8_t __attribute__((ext_vector_type(8)));

typedef __attribute__((address_space(3))) void as3_void;
typedef const __attribute__((address_space(1))) void as1_void_c;

__device__ __forceinline__ void async_copy16(const uint8_t* g, uint8_t* l) {
    __builtin_amdgcn_global_load_lds((as1_void_c*)g, (as3_void*)l, 16, 0, 0);
}

// compiler memory fence + raw workgroup barrier (NO implicit vmcnt drain;
// vmcnt waits are explicit and counted)
#define MEMFENCE() asm volatile("" ::: "memory")
#define BARRIER()  do { MEMFENCE(); __builtin_amdgcn_s_barrier(); MEMFENCE(); } while (0)

// ---------------------------------------------------------------------------
// Kernel 1: unchanged (verified). fp8 convert + norms + s1 + rowsum zero.
// ---------------------------------------------------------------------------
__global__ __launch_bounds__(256) void prep_kernel(
    const float* __restrict__ q, const float* __restrict__ p,
    const float* __restrict__ neg,
    uint8_t* __restrict__ Qb, uint8_t* __restrict__ Nb,
    float* __restrict__ iq, float* __restrict__ inx,
    float* __restrict__ s1, float* __restrict__ rowsum, int B)
{
    const int lane = threadIdx.x & 63;
    const int wid  = threadIdx.x >> 6;
    const int row  = blockIdx.x * 4 + wid;

    if (row < B) {
        const float4* qr = (const float4*)(q + (size_t)row * D);
        const float4* pr = (const float4*)(p + (size_t)row * D);
        int* qo = (int*)(Qb + (size_t)row * D);
        float qq = 0.f, pp = 0.f, qp = 0.f;
        #pragma unroll
        for (int i = 0; i < 4; ++i) {
            const int idx = i * 64 + lane;
            const float4 qv = qr[idx];
            const float4 pv = pr[idx];
            int pk = __builtin_amdgcn_cvt_pk_fp8_f32(qv.x, qv.y, 0, false);
            pk     = __builtin_amdgcn_cvt_pk_fp8_f32(qv.z, qv.w, pk, true);
            qo[idx] = pk;
            qq += qv.x*qv.x + qv.y*qv.y + qv.z*qv.z + qv.w*qv.w;
            pp += pv.x*pv.x + pv.y*pv.y + pv.z*pv.z + pv.w*pv.w;
            qp += qv.x*pv.x + qv.y*pv.y + qv.z*pv.z + qv.w*pv.w;
        }
        #pragma unroll
        for (int off = 32; off > 0; off >>= 1) {
            qq += __shfl_down(qq, off, 64);
            pp += __shfl_down(pp, off, 64);
            qp += __shfl_down(qp, off, 64);
        }
        if (lane == 0) {
            float qnv = sqrtf(qq);
            iq[row] = (TEMP_INV * LOG2E) / fmaxf(qnv, 1e-20f);
            float den = fmaxf(qnv * sqrtf(pp), EPS);
            s1[row] = expf((qp / den) * TEMP_INV);   // exact reference path
            rowsum[row] = 0.0f;
        }
    } else {
        const int r2 = row - B;
        const float4* nr = (const float4*)(neg + (size_t)r2 * D);
        int* no = (int*)(Nb + (size_t)r2 * D);
        float ss = 0.f;
        #pragma unroll
        for (int i = 0; i < 4; ++i) {
            const int idx = i * 64 + lane;
            const float4 nv = nr[idx];
            int pk = __builtin_amdgcn_cvt_pk_fp8_f32(nv.x, nv.y, 0, false);
            pk     = __builtin_amdgcn_cvt_pk_fp8_f32(nv.z, nv.w, pk, true);
            no[idx] = pk;
            ss += nv.x*nv.x + nv.y*nv.y + nv.z*nv.z + nv.w*nv.w;
        }
        #pragma unroll
        for (int off = 32; off > 0; off >>= 1) ss += __shfl_down(ss, off, 64);
        if (lane == 0) inx[r2] = 1.0f / fmaxf(sqrtf(ss), 1e-20f);
    }
}

// ---------------------------------------------------------------------------
// Kernel 2 (round 4): back to the VERIFIED 128x128 / 4-wave / VGPR=84
// footprint (rounds 2-3 proved this toolchain pins 8-wave blocks at 128
// VGPRs -> unavoidable spill for a 256^2 tile). Change vs round-0 kernel:
// minimum-2-phase pipeline (catalog T3 minimum recipe) --
//   double-buffered LDS (2 x 32 KB), stage(k+1) issued BEFORE computing
//   tile k, counted s_waitcnt vmcnt(8) (next tile's 8 loads stay in flight
//   across the barrier; never drains to 0 mid-loop), raw s_barrier,
//   setprio(1) around the MFMA cluster.
// Data maps / swizzle / fragment reads / epilogue are byte-identical to the
// verified round-0 kernel. Staging holds nothing in VGPRs -> register
// footprint unchanged (~84-100), no spill.
// ---------------------------------------------------------------------------
__global__ __launch_bounds__(256) void gemm_exp_rowsum(
    const uint8_t* __restrict__ Qb, const uint8_t* __restrict__ Nb,
    const float* __restrict__ iq, const float* __restrict__ inx,
    float* __restrict__ rowsum)
{
    __shared__ __align__(16) uint8_t As[2][128 * 128];   // 2 x 16 KB
    __shared__ __align__(16) uint8_t Bs[2][128 * 128];   // 2 x 16 KB

    const int tid = threadIdx.x;
    const int i0 = blockIdx.y * 128;   // Q rows
    const int j0 = blockIdx.x * 128;   // Neg rows

    const int lane = tid & 63;
    const int wid  = tid >> 6;
    const int wm   = wid & 1;          // wave row (2x2 wave grid)
    const int wn   = wid >> 1;         // wave col
    const int quad = lane >> 4;
    const int lc   = lane & 15;
    const int xsw  = lc & 7;           // read-side XOR key

    // staging map (verified): thread t -> row r_in = t>>3 (per 32-row round),
    // slot s = t&7; fetch global chunk c = pi^-1(s ^ (r_in&7)); dest = t*16.
    const int r_in = tid >> 3;
    const int slot = tid & 7;
    const int v    = slot ^ (r_in & 7);
    const int csw  = ((v & 3) << 1) | (v >> 2);
    const uint8_t* gA0 = Qb + (size_t)(i0 + r_in) * D + csw * 16;
    const uint8_t* gB0 = Nb + (size_t)(j0 + r_in) * D + csw * 16;

    auto stage = [&](int buf, int kt) {   // 8 global_load_lds / thread
        const uint8_t* ga = gA0 + kt * 128;
        const uint8_t* gb = gB0 + kt * 128;
        #pragma unroll
        for (int c = 0; c < 4; ++c) {
            async_copy16(ga + (size_t)c * (32 * D), &As[buf][tid * 16 + c * 4096]);
            async_copy16(gb + (size_t)c * (32 * D), &Bs[buf][tid * 16 + c * 4096]);
        }
    };

    // LDS read-side swizzle (verified): slot of chunk 2q / 2q+1
    const int slo = (quad ^ xsw) * 16;
    const int shi = slo ^ 64;

    f32x4_t acc[4][4];
    #pragma unroll
    for (int mi = 0; mi < 4; ++mi)
        #pragma unroll
        for (int ni = 0; ni < 4; ++ni)
            acc[mi][ni] = (f32x4_t){0.f, 0.f, 0.f, 0.f};

    union Frag { i32x8_t v8; i32x4_t v4[2]; };

    stage(0, 0);   // prologue: tile 0 in flight

    #pragma unroll
    for (int kt = 0; kt < 8; ++kt) {
        const int cb = kt & 1;
        // issue next tile into the other buffer (its readers finished at the
        // trailing barrier of iteration kt-1)
        if (kt < 7) {
            stage(cb ^ 1, kt + 1);
            // 16 outstanding; wait until only the 8 next-tile loads remain
            asm volatile("s_waitcnt vmcnt(8)" ::: "memory");
        } else {
            asm volatile("s_waitcnt vmcnt(0)" ::: "memory");
        }
        BARRIER();   // all waves' current-tile chunks are in LDS

        const uint8_t* Abase = &As[cb][(wm * 64 + lc) * 128];
        const uint8_t* Bbase = &Bs[cb][(wn * 64 + lc) * 128];

        Frag bfr[4];
        #pragma unroll
        for (int ni = 0; ni < 4; ++ni) {
            bfr[ni].v4[0] = *(const i32x4_t*)(Bbase + ni * 2048 + slo);
            bfr[ni].v4[1] = *(const i32x4_t*)(Bbase + ni * 2048 + shi);
        }
        __builtin_amdgcn_s_setprio(1);
        #pragma unroll
        for (int mi = 0; mi < 4; ++mi) {
            Frag af;
            af.v4[0] = *(const i32x4_t*)(Abase + mi * 2048 + slo);
            af.v4[1] = *(const i32x4_t*)(Abase + mi * 2048 + shi);
            #pragma unroll
            for (int ni = 0; ni < 4; ++ni)
                acc[mi][ni] = __builtin_amdgcn_mfma_scale_f32_16x16x128_f8f6f4(
                    af.v8, bfr[ni].v8, acc[mi][ni],
                    0 /*A=fp8 e4m3*/, 0 /*B=fp8 e4m3*/,
                    0, 127 /*scale A = 2^0*/, 0, 127 /*scale B = 2^0*/);
        }
        __builtin_amdgcn_s_setprio(0);
        BARRIER();   // all waves done reading buf[cb] -> restageable next iter
    }

    // Epilogue (verified): e = exp2(dot * iq_i * in_j); 16-lane row-reduce.
    // C/D layout (16x16): col = lane&15, row = quad*4 + reg.
    float inl[4];
    #pragma unroll
    for (int ni = 0; ni < 4; ++ni)
        inl[ni] = inx[j0 + wn * 64 + ni * 16 + lc];

    #pragma unroll
    for (int mi = 0; mi < 4; ++mi) {
        const int rbase = i0 + wm * 64 + mi * 16 + quad * 4;
        const float4 qv = *(const float4*)&iq[rbase];   // iq includes T^-1*log2e
        float qa[4] = {qv.x, qv.y, qv.z, qv.w};
        float rs[4] = {0.f, 0.f, 0.f, 0.f};
        #pragma unroll
        for (int ni = 0; ni < 4; ++ni) {
            #pragma unroll
            for (int r = 0; r < 4; ++r)
                rs[r] += __builtin_amdgcn_exp2f(acc[mi][ni][r] * qa[r] * inl[ni]);
        }
        #pragma unroll
        for (int m = 1; m < 16; m <<= 1) {
            #pragma unroll
            for (int r = 0; r < 4; ++r) rs[r] += __shfl_xor(rs[r], m, 64);
        }
        if (lc == 0) {
            #pragma unroll
            for (int r = 0; r < 4; ++r) atomicAdd(&rowsum[rbase + r], rs[r]);
        }
    }
}

// ---------------------------------------------------------------------------
// Kernel 3: unchanged (verified). loss = mean_b( log(s1+s2) - log(s1) ).
// ---------------------------------------------------------------------------
__global__ __launch_bounds__(256) void finalize_kernel(
    const float* __restrict__ s1, const float* __restrict__ rowsum,
    float* __restrict__ out, int B, float invN)
{
    __shared__ float red[4];
    const float4* s4 = (const float4*)s1;
    const float4* r4 = (const float4*)rowsum;
    float acc = 0.f;
    for (int i = threadIdx.x; i < B / 4; i += 256) {
        float4 a = s4[i];
        float4 s = r4[i];
        acc += __logf(a.x + s.x * invN) - __logf(a.x);
        acc += __logf(a.y + s.y * invN) - __logf(a.y);
        acc += __logf(a.z + s.z * invN) - __logf(a.z);
        acc += __logf(a.w + s.w * invN) - __logf(a.w);
    }
    #pragma unroll
    for (int off = 32; off > 0; off >>= 1) acc += __shfl_down(acc, off, 64);
    if ((threadIdx.x & 63) == 0) red[threadIdx.x >> 6] = acc;
    __syncthreads();
    if (threadIdx.x == 0)
        out[0] = (red[0] + red[1] + red[2] + red[3]) / (float)B;
}

extern "C" void kernel_launch(void* const* d_in, const int* in_sizes, int n_in,
                              void* d_out, int out_size, void* d_ws, size_t ws_size,
                              hipStream_t stream) {
    const float* q   = (const float*)d_in[0];
    const float* p   = (const float*)d_in[1];
    const float* neg = (const float*)d_in[2];
    const int B = in_sizes[0] / D;
    const int N = in_sizes[2] / D;

    char* ws = (char*)d_ws;
    uint8_t* Qb     = (uint8_t*)ws;
    uint8_t* Nb     = (uint8_t*)(ws + (size_t)B * D);
    float*   iq     = (float*)(ws + (size_t)(B + N) * D);
    float*   inx    = iq + B;
    float*   s1     = inx + N;
    float*   rowsum = s1 + B;

    prep_kernel<<<(B + N) / 4, 256, 0, stream>>>(q, p, neg, Qb, Nb, iq, inx, s1, rowsum, B);
    gemm_exp_rowsum<<<dim3(N / 128, B / 128), 256, 0, stream>>>(Qb, Nb, iq, inx, rowsum);
    finalize_kernel<<<1, 256, 0, stream>>>(s1, rowsum, (float*)d_out, B, 1.0f / (float)N);
}

// Round 5
// 220.513 us; speedup vs baseline: 2.1425x; 1.1541x over previous
//
#include <hip/hip_runtime.h>
#include <hip/hip_bf16.h>
#include <stdint.h>

#define D 1024
#define TEMP_INV (1.0f / 0.92f)
#define LOG2E 1.44269504f
#define EPS 1e-6f

typedef float f32x4_t __attribute__((ext_vector_type(4)));
typedef int   i32x4_t __attribute__((ext_vector_type(4)));
typedef int   i32x8_t __attribute__((ext_vector_type(8)));

typedef __attribute__((address_space(3))) void as3_void;
typedef const __attribute__((address_space(1))) void as1_void_c;

__device__ __forceinline__ void async_copy16(const uint8_t* g, uint8_t* l) {
    __builtin_amdgcn_global_load_lds((as1_void_c*)g, (as3_void*)l, 16, 0, 0);
}

// fp4 e2m1 nearest-value quantize -> 4-bit code {sign<<3 | mag}.
// mag enumeration is monotone: {0, .5, 1, 1.5, 2, 3, 4, 6}; thresholds are
// midpoints so this is round-to-nearest. Reference is unquantized, so only
// error magnitude matters (no tie-convention issue).
__device__ __forceinline__ uint32_t fp4_of(float x) {
    float a = __builtin_fabsf(x);
    uint32_t c;
    c = (a >= 0.25f) ? 1u : 0u;
    c = (a >= 0.75f) ? 2u : c;
    c = (a >= 1.25f) ? 3u : c;
    c = (a >= 1.75f) ? 4u : c;
    c = (a >= 2.5f)  ? 5u : c;
    c = (a >= 3.5f)  ? 6u : c;
    c = (a >= 5.0f)  ? 7u : c;
    return c | ((__float_as_uint(x) >> 28) & 8u);   // sign -> bit 3
}

__device__ __forceinline__ uint32_t pack8_fp4(float4 a0, float4 a1) {
    return  fp4_of(a0.x)        | (fp4_of(a0.y) << 4)  |
           (fp4_of(a0.z) << 8)  | (fp4_of(a0.w) << 12) |
           (fp4_of(a1.x) << 16) | (fp4_of(a1.y) << 20) |
           (fp4_of(a1.z) << 24) | (fp4_of(a1.w) << 28);
}

// undef-extend an i32x4 fragment to the builtin's i32x8 operand (HW reads
// only v[0:3] for fp4; shufflevector -1 lanes emit no movs).
__device__ __forceinline__ i32x8_t widen(i32x4_t v) {
    return __builtin_shufflevector(v, v, 0, 1, 2, 3, -1, -1, -1, -1);
}

// ---------------------------------------------------------------------------
// Kernel 1: fp4 convert (Q, Neg) + exact fp32 norms + s1 + rowsum zero.
// One wave per row; lane handles 8 consecutive floats per pass (2 passes)
// so each lane emits one packed u32 per pass (coalesced row of 128 u32).
// ---------------------------------------------------------------------------
__global__ __launch_bounds__(256) void prep_kernel(
    const float* __restrict__ q, const float* __restrict__ p,
    const float* __restrict__ neg,
    uint8_t* __restrict__ Qb, uint8_t* __restrict__ Nb,
    float* __restrict__ iq, float* __restrict__ inx,
    float* __restrict__ s1, float* __restrict__ rowsum, int B)
{
    const int lane = threadIdx.x & 63;
    const int wid  = threadIdx.x >> 6;
    const int row  = blockIdx.x * 4 + wid;

    if (row < B) {
        const float4* qr = (const float4*)(q + (size_t)row * D);
        const float4* pr = (const float4*)(p + (size_t)row * D);
        uint32_t* qo = (uint32_t*)(Qb + (size_t)row * (D / 2));
        float qq = 0.f, pp = 0.f, qp = 0.f;
        #pragma unroll
        for (int pass = 0; pass < 2; ++pass) {
            const int f4 = pass * 128 + lane * 2;
            const float4 a0 = qr[f4], a1 = qr[f4 + 1];
            const float4 b0 = pr[f4], b1 = pr[f4 + 1];
            qq += a0.x*a0.x + a0.y*a0.y + a0.z*a0.z + a0.w*a0.w
                + a1.x*a1.x + a1.y*a1.y + a1.z*a1.z + a1.w*a1.w;
            pp += b0.x*b0.x + b0.y*b0.y + b0.z*b0.z + b0.w*b0.w
                + b1.x*b1.x + b1.y*b1.y + b1.z*b1.z + b1.w*b1.w;
            qp += a0.x*b0.x + a0.y*b0.y + a0.z*b0.z + a0.w*b0.w
                + a1.x*b1.x + a1.y*b1.y + a1.z*b1.z + a1.w*b1.w;
            qo[pass * 64 + lane] = pack8_fp4(a0, a1);
        }
        #pragma unroll
        for (int off = 32; off > 0; off >>= 1) {
            qq += __shfl_down(qq, off, 64);
            pp += __shfl_down(pp, off, 64);
            qp += __shfl_down(qp, off, 64);
        }
        if (lane == 0) {
            float qnv = sqrtf(qq);
            iq[row] = (TEMP_INV * LOG2E) / fmaxf(qnv, 1e-20f);
            float den = fmaxf(qnv * sqrtf(pp), EPS);
            s1[row] = expf((qp / den) * TEMP_INV);   // exact reference path
            rowsum[row] = 0.0f;
        }
    } else {
        const int r2 = row - B;
        const float4* nr = (const float4*)(neg + (size_t)r2 * D);
        uint32_t* no = (uint32_t*)(Nb + (size_t)r2 * (D / 2));
        float ss = 0.f;
        #pragma unroll
        for (int pass = 0; pass < 2; ++pass) {
            const int f4 = pass * 128 + lane * 2;
            const float4 n0 = nr[f4], n1 = nr[f4 + 1];
            ss += n0.x*n0.x + n0.y*n0.y + n0.z*n0.z + n0.w*n0.w
                + n1.x*n1.x + n1.y*n1.y + n1.z*n1.z + n1.w*n1.w;
            no[pass * 64 + lane] = pack8_fp4(n0, n1);
        }
        #pragma unroll
        for (int off = 32; off > 0; off >>= 1) ss += __shfl_down(ss, off, 64);
        if (lane == 0) inx[r2] = 1.0f / fmaxf(sqrtf(ss), 1e-20f);
    }
}

// ---------------------------------------------------------------------------
// Kernel 2 (round 5): round-0's VERIFIED single-buffered 128x128 structure,
// data switched fp8 -> MX-fp4 (cbsz=blgp=4, unit scales). A K-tile is still
// 128 rows x 128 B, but 128 B now holds K=256 fp4 values -> 4 K-iters
// (half the barrier drains). Staging bytes + pi-chunk swizzle are unchanged.
// Per (mi,ni): two 16x16x128 MFMAs (K-halves). fp4 fragment = one i32x4:
//   K 0..127  -> chunk quad   -> stored slot pi(quad)^xsw       (slo)
//   K 128..255-> chunk quad+4 -> slot pi(quad)^2^xsw = slo^2    (byte ^32)
// Bank check: 8 lanes per 16B slot, all 8 slots covered -> conflict-free.
// ---------------------------------------------------------------------------
__global__ __launch_bounds__(256) void gemm_exp_rowsum(
    const uint8_t* __restrict__ Qb, const uint8_t* __restrict__ Nb,
    const float* __restrict__ iq, const float* __restrict__ inx,
    float* __restrict__ rowsum)
{
    __shared__ __align__(16) uint8_t As[128 * 128];   // 16 KB
    __shared__ __align__(16) uint8_t Bs[128 * 128];   // 16 KB

    const int tid = threadIdx.x;
    const int i0 = blockIdx.y * 128;   // Q rows
    const int j0 = blockIdx.x * 128;   // Neg rows

    const int lane = tid & 63;
    const int wid  = tid >> 6;
    const int wm   = wid & 1;          // wave row (2x2 wave grid)
    const int wn   = wid >> 1;         // wave col
    const int quad = lane >> 4;
    const int lc   = lane & 15;
    const int xsw  = lc & 7;           // read-side XOR key

    const int DB = D / 2;              // 512 B per fp4 row

    // staging map (verified algebra): thread t -> row r_in = t>>3 (per
    // 32-row round), slot s = t&7; fetch chunk c = pi^-1(s ^ (r_in&7)).
    const int r_in = tid >> 3;
    const int slot = tid & 7;
    const int v    = slot ^ (r_in & 7);
    const int csw  = ((v & 3) << 1) | (v >> 2);
    const uint8_t* gA0 = Qb + (size_t)(i0 + r_in) * DB + csw * 16;
    const uint8_t* gB0 = Nb + (size_t)(j0 + r_in) * DB + csw * 16;
    uint8_t* la = As + tid * 16;
    uint8_t* lb = Bs + tid * 16;

    // LDS read bases: row = wm*64 + mi*16 + lc, 128 B/row
    const uint8_t* Abase = As + (size_t)(wm * 64 + lc) * 128;
    const uint8_t* Bbase = Bs + (size_t)(wn * 64 + lc) * 128;
    const int pq  = (quad >> 1) | ((quad & 1) << 2);   // pi(quad)
    const int slo = (pq ^ xsw) * 16;   // slot of chunk quad   (K 0..127)
    const int shi = slo ^ 32;          // slot of chunk quad+4 (K 128..255)

    f32x4_t acc[4][4];
    #pragma unroll
    for (int mi = 0; mi < 4; ++mi)
        #pragma unroll
        for (int ni = 0; ni < 4; ++ni)
            acc[mi][ni] = (f32x4_t){0.f, 0.f, 0.f, 0.f};

    for (int kt = 0; kt < DB; kt += 128) {   // 4 iters (K=256 each)
        __syncthreads();   // protect LDS while other waves still reading
        #pragma unroll
        for (int c = 0; c < 4; ++c) {
            async_copy16(gA0 + kt + c * (32 * DB), la + c * 4096);
            async_copy16(gB0 + kt + c * (32 * DB), lb + c * 4096);
        }
        __syncthreads();   // drains vmcnt(0) before s_barrier

        i32x4_t blo[4], bhi[4];
        #pragma unroll
        for (int ni = 0; ni < 4; ++ni) {
            blo[ni] = *(const i32x4_t*)(Bbase + ni * 2048 + slo);
            bhi[ni] = *(const i32x4_t*)(Bbase + ni * 2048 + shi);
        }
        #pragma unroll
        for (int mi = 0; mi < 4; ++mi) {
            const i32x8_t A0 = widen(*(const i32x4_t*)(Abase + mi * 2048 + slo));
            const i32x8_t A1 = widen(*(const i32x4_t*)(Abase + mi * 2048 + shi));
            #pragma unroll
            for (int ni = 0; ni < 4; ++ni) {
                acc[mi][ni] = __builtin_amdgcn_mfma_scale_f32_16x16x128_f8f6f4(
                    A0, widen(blo[ni]), acc[mi][ni],
                    4 /*cbsz: A=fp4 e2m1*/, 4 /*blgp: B=fp4 e2m1*/,
                    0, 127 /*scale A = 2^0*/, 0, 127 /*scale B = 2^0*/);
                acc[mi][ni] = __builtin_amdgcn_mfma_scale_f32_16x16x128_f8f6f4(
                    A1, widen(bhi[ni]), acc[mi][ni],
                    4, 4, 0, 127, 0, 127);
            }
        }
    }

    // Epilogue (verified, dtype-independent C/D layout): col = lane&15,
    // row = quad*4 + reg. e = exp2(dot * iq_i * in_j); row-reduce; atomic.
    float inl[4];
    #pragma unroll
    for (int ni = 0; ni < 4; ++ni)
        inl[ni] = inx[j0 + wn * 64 + ni * 16 + lc];

    #pragma unroll
    for (int mi = 0; mi < 4; ++mi) {
        const int rbase = i0 + wm * 64 + mi * 16 + quad * 4;
        const float4 qv = *(const float4*)&iq[rbase];   // iq includes T^-1*log2e
        float qa[4] = {qv.x, qv.y, qv.z, qv.w};
        float rs[4] = {0.f, 0.f, 0.f, 0.f};
        #pragma unroll
        for (int ni = 0; ni < 4; ++ni) {
            #pragma unroll
            for (int r = 0; r < 4; ++r)
                rs[r] += __builtin_amdgcn_exp2f(acc[mi][ni][r] * qa[r] * inl[ni]);
        }
        #pragma unroll
        for (int m = 1; m < 16; m <<= 1) {
            #pragma unroll
            for (int r = 0; r < 4; ++r) rs[r] += __shfl_xor(rs[r], m, 64);
        }
        if (lc == 0) {
            #pragma unroll
            for (int r = 0; r < 4; ++r) atomicAdd(&rowsum[rbase + r], rs[r]);
        }
    }
}

// ---------------------------------------------------------------------------
// Kernel 3: unchanged (verified). loss = mean_b( log(s1+s2) - log(s1) ).
// ---------------------------------------------------------------------------
__global__ __launch_bounds__(256) void finalize_kernel(
    const float* __restrict__ s1, const float* __restrict__ rowsum,
    float* __restrict__ out, int B, float invN)
{
    __shared__ float red[4];
    const float4* s4 = (const float4*)s1;
    const float4* r4 = (const float4*)rowsum;
    float acc = 0.f;
    for (int i = threadIdx.x; i < B / 4; i += 256) {
        float4 a = s4[i];
        float4 s = r4[i];
        acc += __logf(a.x + s.x * invN) - __logf(a.x);
        acc += __logf(a.y + s.y * invN) - __logf(a.y);
        acc += __logf(a.z + s.z * invN) - __logf(a.z);
        acc += __logf(a.w + s.w * invN) - __logf(a.w);
    }
    #pragma unroll
    for (int off = 32; off > 0; off >>= 1) acc += __shfl_down(acc, off, 64);
    if ((threadIdx.x & 63) == 0) red[threadIdx.x >> 6] = acc;
    __syncthreads();
    if (threadIdx.x == 0)
        out[0] = (red[0] + red[1] + red[2] + red[3]) / (float)B;
}

extern "C" void kernel_launch(void* const* d_in, const int* in_sizes, int n_in,
                              void* d_out, int out_size, void* d_ws, size_t ws_size,
                              hipStream_t stream) {
    const float* q   = (const float*)d_in[0];
    const float* p   = (const float*)d_in[1];
    const float* neg = (const float*)d_in[2];
    const int B = in_sizes[0] / D;
    const int N = in_sizes[2] / D;

    char* ws = (char*)d_ws;
    uint8_t* Qb     = (uint8_t*)ws;                              // B * D/2
    uint8_t* Nb     = (uint8_t*)(ws + (size_t)B * (D / 2));      // N * D/2
    float*   iq     = (float*)(ws + (size_t)(B + N) * (D / 2));
    float*   inx    = iq + B;
    float*   s1     = inx + N;
    float*   rowsum = s1 + B;

    prep_kernel<<<(B + N) / 4, 256, 0, stream>>>(q, p, neg, Qb, Nb, iq, inx, s1, rowsum, B);
    gemm_exp_rowsum<<<dim3(N / 128, B / 128), 256, 0, stream>>>(Qb, Nb, iq, inx, rowsum);
    finalize_kernel<<<1, 256, 0, stream>>>(s1, rowsum, (float*)d_out, B, 1.0f / (float)N);
}